// Round 5
// baseline (1238.212 us; speedup 1.0000x reference)
//
#include <hip/hip_runtime.h>

typedef unsigned short u16;
typedef unsigned int u32;
typedef __attribute__((ext_vector_type(8))) __bf16 bf16x8;
typedef __attribute__((ext_vector_type(4))) float f32x4;
typedef __attribute__((ext_vector_type(8))) u16 u16x8;
typedef __attribute__((ext_vector_type(4))) float fv4;

#define DEVI __device__ __forceinline__

DEVI float bf2f(u16 u) { union { u32 i; float f; } v; v.i = ((u32)u) << 16; return v.f; }
DEVI u16 f2bf(float f) {
  union { float f; u32 i; } v; v.f = f;
  u32 r = v.i + 0x7fffu + ((v.i >> 16) & 1u);
  return (u16)(r >> 16);
}

#define GLD16(src, dst)                                                        \
  __builtin_amdgcn_global_load_lds(                                            \
      (const __attribute__((address_space(1))) void*)(src),                    \
      (__attribute__((address_space(3))) void*)(dst), 16, 0, 0)

DEVI f32x4 mfma16(bf16x8 a, bf16x8 b, f32x4 c) {
  return __builtin_amdgcn_mfma_f32_16x16x32_bf16(a, b, c, 0, 0, 0);
}

constexpr int S_    = 2048;
constexpr int QD_   = 3072;
constexpr int H_    = 24;
constexpr int N1_   = 33792;  // 3*3072 + 2*12288
constexpr int K1_   = 3072;
constexpr int K2_   = 15360;  // 3072 + 12288
constexpr int N2_   = 3072;
constexpr int MLP_  = 12288;

// ---------------------------------------------------------------- f32 -> bf16
__global__ void k_cvt(const float* __restrict__ in, u16* __restrict__ out) {
  int i = blockIdx.x * blockDim.x + threadIdx.x;  // 8 elems each
  const fv4* p = (const fv4*)in + (size_t)i * 2;
  fv4 a = p[0], b = p[1];
  u16x8 r;
#pragma unroll
  for (int e = 0; e < 4; ++e) { r[e] = f2bf(a[e]); r[4 + e] = f2bf(b[e]); }
  ((u16x8*)out)[i] = r;
}

// ---------------- f32 [R][C] -> bf16 [C][R]: per-thread 8x8 reg transpose.
// 128x128 tile, 256 threads, no LDS (kills the 8-way-conflict scalar reads).
__global__ __launch_bounds__(256)
void k_tconv8(const float* __restrict__ in, u16* __restrict__ out,
              int R, int C) {
  const int t = threadIdx.x;
  const int R8 = t & 15, C8 = t >> 4;
  const int r0 = blockIdx.y * 128, c0 = blockIdx.x * 128;
  const float* src = in + (size_t)(r0 + R8 * 8) * C + c0 + C8 * 8;
  float rf[8][8];
#pragma unroll
  for (int r = 0; r < 8; ++r) {
    fv4 a = *(const fv4*)(src + (size_t)r * C);
    fv4 b = *(const fv4*)(src + (size_t)r * C + 4);
#pragma unroll
    for (int e = 0; e < 4; ++e) { rf[r][e] = a[e]; rf[r][4 + e] = b[e]; }
  }
  u16* dst = out + (size_t)(c0 + C8 * 8) * R + r0 + R8 * 8;
#pragma unroll
  for (int i = 0; i < 8; ++i) {
    u16x8 v;
#pragma unroll
    for (int j = 0; j < 8; ++j) v[j] = f2bf(rf[j][i]);
    *(u16x8*)(dst + (size_t)i * R) = v;
  }
}

// ------------------------------------------------------- m97-structure GEMM
template <int BM, int BN, int WM, int WN, bool OUTF32>
__global__ __launch_bounds__(256)
void k_gemm(const u16* __restrict__ A, const u16* __restrict__ Bt,
            void* __restrict__ Cout, const float* __restrict__ bias,
            int M, int N, int K) {
  constexpr int FM = WM / 16, FN = WN / 16;
  constexpr int WNC = BN / WN;
  __shared__ u16 As[BM * 32];
  __shared__ u16 Bs[BN * 32];
  const int t = threadIdx.x, w = t >> 6, lane = t & 63;
  const int m0 = blockIdx.x * BM, n0 = blockIdx.y * BN;
  const int wr = w / WNC, wc = w % WNC;
  const int g = lane >> 4, rr = lane & 15;
  const int sm = lane >> 2, sk = (lane & 3) * 8;
  f32x4 acc[FM][FN] = {};
  const int nk = K >> 5;
  for (int kt = 0; kt < nk; ++kt) {
    __syncthreads();
    const int kb = kt * 32 + sk;
#pragma unroll
    for (int c = 0; c < BM / 64; ++c) {
      const int ch = w + c * 4;
      GLD16(A + (size_t)(m0 + ch * 16 + sm) * K + kb, &As[ch * 512]);
    }
#pragma unroll
    for (int c = 0; c < BN / 64; ++c) {
      const int ch = w + c * 4;
      GLD16(Bt + (size_t)(n0 + ch * 16 + sm) * K + kb, &Bs[ch * 512]);
    }
    __syncthreads();
    bf16x8 af[FM], bfr[FN];
#pragma unroll
    for (int mi = 0; mi < FM; ++mi)
      af[mi] = *reinterpret_cast<const bf16x8*>(&As[(wr * WM + mi * 16 + rr) * 32 + g * 8]);
#pragma unroll
    for (int ni = 0; ni < FN; ++ni)
      bfr[ni] = *reinterpret_cast<const bf16x8*>(&Bs[(wc * WN + ni * 16 + rr) * 32 + g * 8]);
#pragma unroll
    for (int mi = 0; mi < FM; ++mi)
#pragma unroll
      for (int ni = 0; ni < FN; ++ni)
        acc[mi][ni] = mfma16(af[mi], bfr[ni], acc[mi][ni]);
  }
#pragma unroll
  for (int mi = 0; mi < FM; ++mi)
#pragma unroll
    for (int ni = 0; ni < FN; ++ni) {
      const int row = m0 + wr * WM + mi * 16 + g * 4;
      const int col = n0 + wc * WN + ni * 16 + rr;
#pragma unroll
      for (int j = 0; j < 4; ++j) {
        if constexpr (OUTF32)
          ((float*)Cout)[(size_t)(row + j) * N + col] = acc[mi][ni][j] + bias[col];
        else
          ((u16*)Cout)[(size_t)(row + j) * N + col] = f2bf(acc[mi][ni][j]);
      }
    }
}

// ---------------------- 256x256 / BK=64 8-phase GEMM (T1+T2+T3+T4+T5 port)
// Template-faithful waits: lgkmcnt(8) pre-barrier on the 12-read phase and
// lgkmcnt(0) right after each opening barrier (m201 structure).
#define BARX() asm volatile("s_barrier" ::: "memory")
#define LGKM0() asm volatile("s_waitcnt lgkmcnt(0)" ::: "memory")
__global__ __launch_bounds__(512, 2)
void k_gemm256(const u16* __restrict__ A, const u16* __restrict__ Bt,
               u16* __restrict__ C, int N, int K, int nbm) {
  extern __shared__ char smem[];
  const int t = threadIdx.x;
  const int w = t >> 6, lane = t & 63;
  const int wr = w >> 2, wc = w & 3, bh = wc >> 1;
  const int g = lane >> 4, rr = lane & 15;
  const int nwg = gridDim.x, bid = blockIdx.x;
  const int swz = (bid & 7) * (nwg >> 3) + (bid >> 3);
  const int m0 = (swz % nbm) * 256;
  const int n0 = (swz / nbm) * 256;
  const int o = t * 16;
  const int ou = o ^ (((o >> 9) & 1) << 5);
  const int srow = ((ou >> 10) >> 1) * 16 + ((ou >> 6) & 15);
  const int scol = ((ou >> 10) & 1) * 32 + ((ou & 63) >> 1);
  const int soff = (rr * 64 + g * 16) ^ (((rr >> 3) & 1) << 5);
  const int bnoff = (wc & 1) * 8192;
  const int nk = K >> 6;

  const u16* Arow = A + (size_t)(m0 + srow) * K + scol;
  const u16* Brow = Bt + (size_t)(n0 + srow) * K + scol;
#define LDSA(buf, h) (smem + ((buf) * 2 + (h)) * 16384 + w * 1024)
#define LDSB(buf, h) (smem + 65536 + ((buf) * 2 + (h)) * 16384 + w * 1024)
#define STG(rowptr, h, k0, dst)                                   \
  do {                                                            \
    const u16* _s = (rowptr) + (size_t)(h) * 128 * K + (k0);      \
    GLD16(_s, (dst));                                             \
    GLD16(_s + (size_t)64 * K, (dst) + 8192);                     \
  } while (0)

  // prologue: tile0 A+B, tile1 B, tile1 A-half0. vmcnt(6) leaves those 3.
  STG(Arow, 0, 0, LDSA(0, 0));
  STG(Arow, 1, 0, LDSA(0, 1));
  STG(Brow, 0, 0, LDSB(0, 0));
  STG(Brow, 1, 0, LDSB(0, 1));
  STG(Brow, 0, 64, LDSB(1, 0));
  STG(Brow, 1, 64, LDSB(1, 1));
  STG(Arow, 0, 64, LDSA(1, 0));
  asm volatile("s_waitcnt vmcnt(6)" ::: "memory");
  BARX();

  f32x4 acc[8][4] = {};
  for (int j = 0; j < nk; ++j) {
    const int b = j & 1;
    const char* Ab = smem + ((b << 1) + wr) * 16384;
    const char* Bb = smem + 65536 + ((b << 1) + bh) * 16384;
    const int jb = (j + 2 < nk) ? j + 2 : nk - 1;  // clamped re-stage is safe
    bf16x8 aL[4][2], aH[4][2], bL[2][2], bH[2][2];
    // ---- P1: read aL + bL; stage A1(j+1) -> other buf (guarded at tail)
#pragma unroll
    for (int m = 0; m < 4; ++m)
#pragma unroll
      for (int kk = 0; kk < 2; ++kk)
        aL[m][kk] = *(const bf16x8*)(Ab + m * 2048 + kk * 1024 + soff);
#pragma unroll
    for (int n = 0; n < 2; ++n)
#pragma unroll
      for (int kk = 0; kk < 2; ++kk)
        bL[n][kk] = *(const bf16x8*)(Bb + bnoff + n * 2048 + kk * 1024 + soff);
    if (j + 1 < nk) STG(Arow, 1, (j + 1) * 64, LDSA((j + 1) & 1, 1));
    asm volatile("s_waitcnt lgkmcnt(8)" ::: "memory");
    BARX();
    LGKM0();
    __builtin_amdgcn_s_setprio(1);
#pragma unroll
    for (int m = 0; m < 4; ++m)
#pragma unroll
      for (int n = 0; n < 2; ++n)
#pragma unroll
        for (int kk = 0; kk < 2; ++kk)
          acc[m][n] = mfma16(aL[m][kk], bL[n][kk], acc[m][n]);
    __builtin_amdgcn_s_setprio(0);
    BARX();
    // ---- P2: read bH (no stage)
#pragma unroll
    for (int n = 0; n < 2; ++n)
#pragma unroll
      for (int kk = 0; kk < 2; ++kk)
        bH[n][kk] = *(const bf16x8*)(Bb + bnoff + (n + 2) * 2048 + kk * 1024 + soff);
    BARX();
    LGKM0();
    __builtin_amdgcn_s_setprio(1);
#pragma unroll
    for (int m = 0; m < 4; ++m)
#pragma unroll
      for (int n = 0; n < 2; ++n)
#pragma unroll
        for (int kk = 0; kk < 2; ++kk)
          acc[m][n + 2] = mfma16(aL[m][kk], bH[n][kk], acc[m][n + 2]);
    __builtin_amdgcn_s_setprio(0);
    BARX();
    // ---- P3: read aH; stage B0(j+2) -> own buf (B reads done in P2)
#pragma unroll
    for (int m = 0; m < 4; ++m)
#pragma unroll
      for (int kk = 0; kk < 2; ++kk)
        aH[m][kk] = *(const bf16x8*)(Ab + (m + 4) * 2048 + kk * 1024 + soff);
    STG(Brow, 0, jb * 64, LDSB(b, 0));
    BARX();
    LGKM0();
    __builtin_amdgcn_s_setprio(1);
#pragma unroll
    for (int m = 0; m < 4; ++m)
#pragma unroll
      for (int n = 0; n < 2; ++n)
#pragma unroll
        for (int kk = 0; kk < 2; ++kk)
          acc[m + 4][n] = mfma16(aH[m][kk], bL[n][kk], acc[m + 4][n]);
    __builtin_amdgcn_s_setprio(0);
    BARX();
    // ---- P4: stage B1(j+2) + A0(j+2); counted vmcnt(6) drains A1(j+1)
    STG(Brow, 1, jb * 64, LDSB(b, 1));
    STG(Arow, 0, jb * 64, LDSA(b, 0));
    asm volatile("s_waitcnt vmcnt(6)" ::: "memory");
    BARX();
    LGKM0();
    __builtin_amdgcn_s_setprio(1);
#pragma unroll
    for (int m = 0; m < 4; ++m)
#pragma unroll
      for (int n = 0; n < 2; ++n)
#pragma unroll
        for (int kk = 0; kk < 2; ++kk)
          acc[m + 4][n + 2] = mfma16(aH[m][kk], bH[n][kk], acc[m + 4][n + 2]);
    __builtin_amdgcn_s_setprio(0);
    BARX();
  }
#pragma unroll
  for (int m = 0; m < 8; ++m)
#pragma unroll
    for (int n = 0; n < 4; ++n) {
      const int row = m0 + wr * 128 + m * 16 + g * 4;
      const int col = n0 + wc * 64 + n * 16 + rr;
#pragma unroll
      for (int jj = 0; jj < 4; ++jj)
        C[(size_t)(row + jj) * N + col] = f2bf(acc[m][n][jj]);
    }
#undef LDSA
#undef LDSB
#undef STG
}

// ------------------------------------- RMSNorm + interleaved RoPE on q,k rows
__global__ __launch_bounds__(256)
void k_qknr(u16* __restrict__ h, const float* __restrict__ cosT,
            const float* __restrict__ sinT, const float* __restrict__ wq,
            const float* __restrict__ wk) {
  const int row = blockIdx.x * 4 + (threadIdx.x >> 6);
  const int lane = threadIdx.x & 63;
  const int s = row / 48;
  const int r2 = row - s * 48;
  const int qk = r2 / 24;
  const int head = r2 - qk * 24;
  u16* base = h + (size_t)s * N1_ + qk * 3072 + head * 128;
  u32 pv = *(const u32*)(base + 2 * lane);
  float x1 = bf2f((u16)(pv & 0xffff)), x2 = bf2f((u16)(pv >> 16));
  float ss = x1 * x1 + x2 * x2;
#pragma unroll
  for (int off = 32; off >= 1; off >>= 1) ss += __shfl_xor(ss, off);
  const float inv = rsqrtf(ss * (1.0f / 128.0f) + 1e-5f);
  const float* wv = qk ? wk : wq;
  const float w1 = wv[2 * lane], w2 = wv[2 * lane + 1];
  const float c = cosT[s * 64 + lane], sn = sinT[s * 64 + lane];
  float xn1 = x1 * inv * w1, xn2 = x2 * inv * w2;
  float r1 = xn1 * c - xn2 * sn;
  float r2v = xn2 * c + xn1 * sn;
  if (!qk) { r1 *= 0.08838834764831845f; r2v *= 0.08838834764831845f; }
  *(u32*)(base + 2 * lane) = (u32)f2bf(r1) | ((u32)f2bf(r2v) << 16);
}

// --------------------------------------------- V^T per head: vt[h*128+d][s]
__global__ __launch_bounds__(256)
void k_vt(const u16* __restrict__ h, u16* __restrict__ vt) {
  __shared__ u16 tile[64][144];
  const int t = threadIdx.x;
  const int head = blockIdx.y;
  const int s0 = blockIdx.x * 64;
  {
    const int sl = t >> 2, cc = t & 3;
    const u16* src = h + (size_t)(s0 + sl) * N1_ + 6144 + head * 128 + cc * 32;
#pragma unroll
    for (int q = 0; q < 4; ++q)
      *(u16x8*)&tile[sl][cc * 32 + q * 8] = *(const u16x8*)(src + q * 8);
  }
  __syncthreads();
  {
    const int d = t & 127, half = t >> 7;
    u16* dst = vt + ((size_t)head * 128 + d) * S_ + s0 + half * 32;
#pragma unroll
    for (int q = 0; q < 4; ++q) {
      u16x8 v;
#pragma unroll
      for (int e = 0; e < 8; ++e) v[e] = tile[half * 32 + q * 8 + e][d];
      *(u16x8*)(dst + q * 8) = v;
    }
  }
}

// ------------------------------------------------------------ flash attention
__global__ __launch_bounds__(256)
void k_attn(const u16* __restrict__ h, const u16* __restrict__ vt,
            u16* __restrict__ cc) {
  extern __shared__ char smem[];
  char* KsB = smem;           // 2 x 16KB
  char* VsB = smem + 32768;   // 2 x 16KB
  const int t = threadIdx.x, w = t >> 6, lane = t & 63;
  const int g = lane >> 4, c = lane & 15;
  u16* Pw = (u16*)(smem + 65536 + w * 2304);  // [16][72]
  const int head = blockIdx.y;
  const int q0 = blockIdx.x * 64 + w * 16;
  const int wb = w * 1024;

  const u16* ksrc[4];
  const u16* vsrc[4];
#pragma unroll
  for (int p = 0; p < 4; ++p) {
    const int o = p * 4096 + wb + lane * 16;
    {
      const int kc = o >> 12, r = (o >> 6) & 63, db = o & 63;
      ksrc[p] = h + (size_t)r * N1_ + 3072 + head * 128 + kc * 32 + db / 2;
    }
    {
      const int ks = o >> 13, d = (o >> 6) & 127, db = o & 63;
      vsrc[p] = vt + (size_t)(head * 128 + d) * S_ + ks * 32 + db / 2;
    }
  }
#define STAGEA(ts, buf)                                                     \
  do {                                                                      \
    const size_t _ka = (size_t)(ts) * 64 * N1_;                             \
    const int _kv = (ts) * 64;                                              \
    _Pragma("unroll") for (int p = 0; p < 4; ++p)                           \
        GLD16(ksrc[p] + _ka, KsB + (buf) * 16384 + p * 4096 + wb);          \
    _Pragma("unroll") for (int p = 0; p < 4; ++p)                           \
        GLD16(vsrc[p] + _kv, VsB + (buf) * 16384 + p * 4096 + wb);          \
  } while (0)

  bf16x8 aq[4];
  {
    const u16* qr = h + (size_t)(q0 + c) * N1_ + head * 128;
#pragma unroll
    for (int kc = 0; kc < 4; ++kc)
      aq[kc] = *reinterpret_cast<const bf16x8*>(qr + kc * 32 + g * 8);
  }
  f32x4 o[8] = {};
  float m_[4] = {-1e30f, -1e30f, -1e30f, -1e30f};
  float l_[4] = {0.f, 0.f, 0.f, 0.f};

  STAGEA(0, 0);
  STAGEA(1, 1);
  asm volatile("s_waitcnt vmcnt(8)" ::: "memory");
  __builtin_amdgcn_s_barrier();

  for (int tt = 0; tt < 32; ++tt) {
    const int buf = tt & 1;
    const char* Kb = KsB + buf * 16384;
    const char* Vb = VsB + buf * 16384;
    f32x4 sc[4] = {};
    __builtin_amdgcn_s_setprio(1);
#pragma unroll
    for (int nf = 0; nf < 4; ++nf)
#pragma unroll
      for (int kc = 0; kc < 4; ++kc) {
        bf16x8 bk = *(const bf16x8*)(Kb + kc * 4096 + (nf * 16 + c) * 64 + g * 16);
        sc[nf] = mfma16(aq[kc], bk, sc[nf]);
      }
    __builtin_amdgcn_s_setprio(0);
    float rmax[4];
#pragma unroll
    for (int j = 0; j < 4; ++j)
      rmax[j] = fmaxf(fmaxf(sc[0][j], sc[1][j]), fmaxf(sc[2][j], sc[3][j]));
#pragma unroll
    for (int j = 0; j < 4; ++j)
#pragma unroll
      for (int off = 8; off >= 1; off >>= 1)
        rmax[j] = fmaxf(rmax[j], __shfl_xor(rmax[j], off));
    float al[4], rs[4];
#pragma unroll
    for (int j = 0; j < 4; ++j) {
      const float mn = fmaxf(m_[j], rmax[j]);
      al[j] = __expf(m_[j] - mn);
      m_[j] = mn;
      rs[j] = 0.f;
    }
#pragma unroll
    for (int nf = 0; nf < 4; ++nf)
#pragma unroll
      for (int j = 0; j < 4; ++j) {
        const float pr = __expf(sc[nf][j] - m_[j]);
        sc[nf][j] = pr;
        rs[j] += pr;
      }
#pragma unroll
    for (int j = 0; j < 4; ++j) {
#pragma unroll
      for (int off = 8; off >= 1; off >>= 1) rs[j] += __shfl_xor(rs[j], off);
      l_[j] = l_[j] * al[j] + rs[j];
    }
#pragma unroll
    for (int of = 0; of < 8; ++of)
#pragma unroll
      for (int j = 0; j < 4; ++j) o[of][j] *= al[j];
#pragma unroll
    for (int nf = 0; nf < 4; ++nf)
#pragma unroll
      for (int j = 0; j < 4; ++j)
        Pw[(g * 4 + j) * 72 + nf * 16 + c] = f2bf(sc[nf][j]);
    asm volatile("s_waitcnt lgkmcnt(0)" ::: "memory");
    bf16x8 ap[2];
#pragma unroll
    for (int ks = 0; ks < 2; ++ks)
      ap[ks] = *(const bf16x8*)(Pw + c * 72 + ks * 32 + g * 8);
    __builtin_amdgcn_s_setprio(1);
#pragma unroll
    for (int of = 0; of < 8; ++of)
#pragma unroll
      for (int ks = 0; ks < 2; ++ks) {
        bf16x8 bv = *(const bf16x8*)(Vb + ks * 8192 + (of * 16 + c) * 64 + g * 16);
        o[of] = mfma16(ap[ks], bv, o[of]);
      }
    __builtin_amdgcn_s_setprio(0);
    __builtin_amdgcn_s_barrier();
    const int tn = (tt + 2 < 32) ? tt + 2 : 31;
    STAGEA(tn, buf);
    asm volatile("s_waitcnt vmcnt(8)" ::: "memory");
    __builtin_amdgcn_s_barrier();
  }
  float inv[4];
#pragma unroll
  for (int j = 0; j < 4; ++j) inv[j] = 1.0f / l_[j];
#pragma unroll
  for (int of = 0; of < 8; ++of)
#pragma unroll
    for (int j = 0; j < 4; ++j)
      cc[(size_t)(q0 + g * 4 + j) * K2_ + head * 128 + of * 16 + c] =
          f2bf(o[of][j] * inv[j]);
#undef STAGEA
}

// --------------------------------------------------- silu(x1)*x2 -> concat
__global__ void k_mlpact(const u16* __restrict__ h, u16* __restrict__ cc) {
  const int i = blockIdx.x * blockDim.x + threadIdx.x;
  const int s = i / 1536;
  const int j8 = i - s * 1536;
  const u16x8 a8 = *((const u16x8*)(h + (size_t)s * N1_ + 9216) + j8);
  const u16x8 b8 = *((const u16x8*)(h + (size_t)s * N1_ + 21504) + j8);
  u16x8 r;
#pragma unroll
  for (int e = 0; e < 8; ++e) {
    float a = bf2f(a8[e]), b = bf2f(b8[e]);
    float sv = a / (1.0f + expf(-a));
    r[e] = f2bf(sv * b);
  }
  *((u16x8*)(cc + (size_t)s * K2_ + 3072) + j8) = r;
}

// ---------------------------------------------------------------------------
extern "C" void kernel_launch(void* const* d_in, const int* in_sizes, int n_in,
                              void* d_out, int out_size, void* d_ws,
                              size_t ws_size, hipStream_t stream) {
  const float* hs   = (const float*)d_in[0];
  const float* cosT = (const float*)d_in[1];
  const float* sinT = (const float*)d_in[2];
  const float* W1   = (const float*)d_in[3];
  const float* wq   = (const float*)d_in[4];
  const float* wk   = (const float*)d_in[5];
  const float* W2   = (const float*)d_in[6];
  const float* bo   = (const float*)d_in[7];
  float* out = (float*)d_out;

  char* p = (char*)d_ws;
  u16* Abf  = (u16*)p; p += (size_t)S_ * K1_ * 2;
  u16* W1t  = (u16*)p; p += (size_t)N1_ * K1_ * 2;
  u16* W2t  = (u16*)p; p += (size_t)N2_ * K2_ * 2;
  u16* Hbuf = (u16*)p; p += (size_t)S_ * N1_ * 2;
  u16* Vt   = (u16*)p; p += (size_t)H_ * 128 * S_ * 2;
  u16* CC   = (u16*)p; p += (size_t)S_ * K2_ * 2;
  if ((size_t)(p - (char*)d_ws) > ws_size) return;

  k_cvt<<<(S_ * K1_) / (256 * 8), 256, 0, stream>>>(hs, Abf);
  // W1 [3072][33792] -> W1t [33792][3072]; W2 [15360][3072] -> W2t [3072][15360]
  k_tconv8<<<dim3(N1_ / 128, K1_ / 128), 256, 0, stream>>>(W1, W1t, K1_, N1_);
  k_tconv8<<<dim3(N2_ / 128, K2_ / 128), 256, 0, stream>>>(W2, W2t, K2_, N2_);

  hipError_t aerr = hipFuncSetAttribute(
      reinterpret_cast<const void*>(k_gemm256),
      hipFuncAttributeMaxDynamicSharedMemorySize, 131072);
  if (aerr == hipSuccess) {
    k_gemm256<<<dim3(1056), 512, 131072, stream>>>(Abf, W1t, Hbuf,
                                                   N1_, K1_, 8);
  } else {
    k_gemm<128, 128, 64, 64, false>
        <<<dim3(S_ / 128, N1_ / 128), 256, 0, stream>>>(Abf, W1t, Hbuf, nullptr,
                                                        S_, N1_, K1_);
  }
  k_qknr<<<(S_ * 2 * H_) / 4, 256, 0, stream>>>(Hbuf, cosT, sinT, wq, wk);
  k_vt<<<dim3(S_ / 64, H_), 256, 0, stream>>>(Hbuf, Vt);
  (void)hipFuncSetAttribute(reinterpret_cast<const void*>(k_attn),
                            hipFuncAttributeMaxDynamicSharedMemorySize, 75776);
  k_attn<<<dim3(S_ / 64, H_), 256, 75776, stream>>>(Hbuf, Vt, CC);
  k_mlpact<<<(S_ * MLP_) / (256 * 8), 256, 0, stream>>>(Hbuf, CC);
  k_gemm<128, 128, 64, 64, true>
      <<<dim3(S_ / 128, N2_ / 128), 256, 0, stream>>>(CC, W2t, out, bo,
                                                      S_, N2_, K2_);
}

// Round 6
// 1018.794 us; speedup vs baseline: 1.2154x; 1.2154x over previous
//
#include <hip/hip_runtime.h>

typedef unsigned short u16;
typedef unsigned int u32;
typedef __attribute__((ext_vector_type(8))) __bf16 bf16x8;
typedef __attribute__((ext_vector_type(4))) float f32x4;
typedef __attribute__((ext_vector_type(8))) u16 u16x8;
typedef __attribute__((ext_vector_type(4))) float fv4;

#define DEVI __device__ __forceinline__

DEVI float bf2f(u16 u) { union { u32 i; float f; } v; v.i = ((u32)u) << 16; return v.f; }
DEVI u16 f2bf(float f) {
  union { float f; u32 i; } v; v.f = f;
  u32 r = v.i + 0x7fffu + ((v.i >> 16) & 1u);
  return (u16)(r >> 16);
}

#define GLD16(src, dst)                                                        \
  __builtin_amdgcn_global_load_lds(                                            \
      (const __attribute__((address_space(1))) void*)(src),                    \
      (__attribute__((address_space(3))) void*)(dst), 16, 0, 0)

DEVI f32x4 mfma16(bf16x8 a, bf16x8 b, f32x4 c) {
  return __builtin_amdgcn_mfma_f32_16x16x32_bf16(a, b, c, 0, 0, 0);
}

constexpr int S_    = 2048;
constexpr int QD_   = 3072;
constexpr int H_    = 24;
constexpr int N1_   = 33792;  // 3*3072 + 2*12288
constexpr int K1_   = 3072;
constexpr int K2_   = 15360;  // 3072 + 12288
constexpr int N2_   = 3072;
constexpr int MLP_  = 12288;

// ---------------------------------------------------------------- f32 -> bf16
__global__ void k_cvt(const float* __restrict__ in, u16* __restrict__ out) {
  int i = blockIdx.x * blockDim.x + threadIdx.x;  // 8 elems each
  const fv4* p = (const fv4*)in + (size_t)i * 2;
  fv4 a = p[0], b = p[1];
  u16x8 r;
#pragma unroll
  for (int e = 0; e < 4; ++e) { r[e] = f2bf(a[e]); r[4 + e] = f2bf(b[e]); }
  ((u16x8*)out)[i] = r;
}

// ---------------- f32 [R][C] -> bf16 [C][R]: per-thread 8x8 reg transpose.
__global__ __launch_bounds__(256)
void k_tconv8(const float* __restrict__ in, u16* __restrict__ out,
              int R, int C) {
  const int t = threadIdx.x;
  const int R8 = t & 15, C8 = t >> 4;
  const int r0 = blockIdx.y * 128, c0 = blockIdx.x * 128;
  const float* src = in + (size_t)(r0 + R8 * 8) * C + c0 + C8 * 8;
  float rf[8][8];
#pragma unroll
  for (int r = 0; r < 8; ++r) {
    fv4 a = *(const fv4*)(src + (size_t)r * C);
    fv4 b = *(const fv4*)(src + (size_t)r * C + 4);
#pragma unroll
    for (int e = 0; e < 4; ++e) { rf[r][e] = a[e]; rf[r][4 + e] = b[e]; }
  }
  u16* dst = out + (size_t)(c0 + C8 * 8) * R + r0 + R8 * 8;
#pragma unroll
  for (int i = 0; i < 8; ++i) {
    u16x8 v;
#pragma unroll
    for (int j = 0; j < 8; ++j) v[j] = f2bf(rf[j][i]);
    *(u16x8*)(dst + (size_t)i * R) = v;
  }
}

// ------------------------------------------------------- m97-structure GEMM
// (fallback path only)
template <int BM, int BN, int WM, int WN, bool OUTF32>
__global__ __launch_bounds__(256)
void k_gemm(const u16* __restrict__ A, const u16* __restrict__ Bt,
            void* __restrict__ Cout, const float* __restrict__ bias,
            int M, int N, int K) {
  constexpr int FM = WM / 16, FN = WN / 16;
  constexpr int WNC = BN / WN;
  __shared__ u16 As[BM * 32];
  __shared__ u16 Bs[BN * 32];
  const int t = threadIdx.x, w = t >> 6, lane = t & 63;
  const int m0 = blockIdx.x * BM, n0 = blockIdx.y * BN;
  const int wr = w / WNC, wc = w % WNC;
  const int g = lane >> 4, rr = lane & 15;
  const int sm = lane >> 2, sk = (lane & 3) * 8;
  f32x4 acc[FM][FN] = {};
  const int nk = K >> 5;
  for (int kt = 0; kt < nk; ++kt) {
    __syncthreads();
    const int kb = kt * 32 + sk;
#pragma unroll
    for (int c = 0; c < BM / 64; ++c) {
      const int ch = w + c * 4;
      GLD16(A + (size_t)(m0 + ch * 16 + sm) * K + kb, &As[ch * 512]);
    }
#pragma unroll
    for (int c = 0; c < BN / 64; ++c) {
      const int ch = w + c * 4;
      GLD16(Bt + (size_t)(n0 + ch * 16 + sm) * K + kb, &Bs[ch * 512]);
    }
    __syncthreads();
    bf16x8 af[FM], bfr[FN];
#pragma unroll
    for (int mi = 0; mi < FM; ++mi)
      af[mi] = *reinterpret_cast<const bf16x8*>(&As[(wr * WM + mi * 16 + rr) * 32 + g * 8]);
#pragma unroll
    for (int ni = 0; ni < FN; ++ni)
      bfr[ni] = *reinterpret_cast<const bf16x8*>(&Bs[(wc * WN + ni * 16 + rr) * 32 + g * 8]);
#pragma unroll
    for (int mi = 0; mi < FM; ++mi)
#pragma unroll
      for (int ni = 0; ni < FN; ++ni)
        acc[mi][ni] = mfma16(af[mi], bfr[ni], acc[mi][ni]);
  }
#pragma unroll
  for (int mi = 0; mi < FM; ++mi)
#pragma unroll
    for (int ni = 0; ni < FN; ++ni) {
      const int row = m0 + wr * WM + mi * 16 + g * 4;
      const int col = n0 + wc * WN + ni * 16 + rr;
#pragma unroll
      for (int j = 0; j < 4; ++j) {
        if constexpr (OUTF32)
          ((float*)Cout)[(size_t)(row + j) * N + col] = acc[mi][ni][j] + bias[col];
        else
          ((u16*)Cout)[(size_t)(row + j) * N + col] = f2bf(acc[mi][ni][j]);
      }
    }
}

// ---------------------- 256x256 / BK=64 8-phase GEMM (T1..T5), generalized:
// grid tile id swz -> (z, m, n); block computes K-range [z*nkt*64, ...) and
// writes bf16 C-plane z (split-K). zmul = nbm*nbn; nkt = K-tiles per block.
#define BARX() asm volatile("s_barrier" ::: "memory")
#define LGKM0() asm volatile("s_waitcnt lgkmcnt(0)" ::: "memory")
__global__ __launch_bounds__(512, 2)
void k_gemm256(const u16* __restrict__ A, const u16* __restrict__ Bt,
               u16* __restrict__ C, int N, int K, int nbm, int zmul, int nkt) {
  extern __shared__ char smem[];
  const int t = threadIdx.x;
  const int w = t >> 6, lane = t & 63;
  const int wr = w >> 2, wc = w & 3, bh = wc >> 1;
  const int g = lane >> 4, rr = lane & 15;
  const int nwg = gridDim.x, bid = blockIdx.x;
  const int swz = (bid & 7) * (nwg >> 3) + (bid >> 3);
  const int zz = swz / zmul;
  const int rem = swz - zz * zmul;
  const int m0 = (rem % nbm) * 256;
  const int n0 = (rem / nbm) * 256;
  const int koff = zz * nkt * 64;
  const int o = t * 16;
  const int ou = o ^ (((o >> 9) & 1) << 5);
  const int srow = ((ou >> 10) >> 1) * 16 + ((ou >> 6) & 15);
  const int scol = ((ou >> 10) & 1) * 32 + ((ou & 63) >> 1);
  const int soff = (rr * 64 + g * 16) ^ (((rr >> 3) & 1) << 5);
  const int bnoff = (wc & 1) * 8192;
  const int nk = nkt;

  const u16* Arow = A + (size_t)(m0 + srow) * K + koff + scol;
  const u16* Brow = Bt + (size_t)(n0 + srow) * K + koff + scol;
  u16* Cz = C + (size_t)zz * ((size_t)nbm * 256) * N;
#define LDSA(buf, h) (smem + ((buf) * 2 + (h)) * 16384 + w * 1024)
#define LDSB(buf, h) (smem + 65536 + ((buf) * 2 + (h)) * 16384 + w * 1024)
#define STG(rowptr, h, k0, dst)                                   \
  do {                                                            \
    const u16* _s = (rowptr) + (size_t)(h) * 128 * K + (k0);      \
    GLD16(_s, (dst));                                             \
    GLD16(_s + (size_t)64 * K, (dst) + 8192);                     \
  } while (0)

  // prologue: tile0 A+B, tile1 B, tile1 A-half0. vmcnt(6) leaves those 3.
  STG(Arow, 0, 0, LDSA(0, 0));
  STG(Arow, 1, 0, LDSA(0, 1));
  STG(Brow, 0, 0, LDSB(0, 0));
  STG(Brow, 1, 0, LDSB(0, 1));
  STG(Brow, 0, 64, LDSB(1, 0));
  STG(Brow, 1, 64, LDSB(1, 1));
  STG(Arow, 0, 64, LDSA(1, 0));
  asm volatile("s_waitcnt vmcnt(6)" ::: "memory");
  BARX();

  f32x4 acc[8][4] = {};
  for (int j = 0; j < nk; ++j) {
    const int b = j & 1;
    const char* Ab = smem + ((b << 1) + wr) * 16384;
    const char* Bb = smem + 65536 + ((b << 1) + bh) * 16384;
    const int jb = (j + 2 < nk) ? j + 2 : nk - 1;  // clamped re-stage is safe
    bf16x8 aL[4][2], aH[4][2], bL[2][2], bH[2][2];
    // ---- P1: read aL + bL; stage A1(j+1) -> other buf (guarded at tail)
#pragma unroll
    for (int m = 0; m < 4; ++m)
#pragma unroll
      for (int kk = 0; kk < 2; ++kk)
        aL[m][kk] = *(const bf16x8*)(Ab + m * 2048 + kk * 1024 + soff);
#pragma unroll
    for (int n = 0; n < 2; ++n)
#pragma unroll
      for (int kk = 0; kk < 2; ++kk)
        bL[n][kk] = *(const bf16x8*)(Bb + bnoff + n * 2048 + kk * 1024 + soff);
    if (j + 1 < nk) STG(Arow, 1, (j + 1) * 64, LDSA((j + 1) & 1, 1));
    asm volatile("s_waitcnt lgkmcnt(8)" ::: "memory");
    BARX();
    LGKM0();
    __builtin_amdgcn_s_setprio(1);
#pragma unroll
    for (int m = 0; m < 4; ++m)
#pragma unroll
      for (int n = 0; n < 2; ++n)
#pragma unroll
        for (int kk = 0; kk < 2; ++kk)
          acc[m][n] = mfma16(aL[m][kk], bL[n][kk], acc[m][n]);
    __builtin_amdgcn_s_setprio(0);
    BARX();
    // ---- P2: read bH (no stage)
#pragma unroll
    for (int n = 0; n < 2; ++n)
#pragma unroll
      for (int kk = 0; kk < 2; ++kk)
        bH[n][kk] = *(const bf16x8*)(Bb + bnoff + (n + 2) * 2048 + kk * 1024 + soff);
    BARX();
    LGKM0();
    __builtin_amdgcn_s_setprio(1);
#pragma unroll
    for (int m = 0; m < 4; ++m)
#pragma unroll
      for (int n = 0; n < 2; ++n)
#pragma unroll
        for (int kk = 0; kk < 2; ++kk)
          acc[m][n + 2] = mfma16(aL[m][kk], bH[n][kk], acc[m][n + 2]);
    __builtin_amdgcn_s_setprio(0);
    BARX();
    // ---- P3: read aH; stage B0(j+2) -> own buf (B reads done in P2)
#pragma unroll
    for (int m = 0; m < 4; ++m)
#pragma unroll
      for (int kk = 0; kk < 2; ++kk)
        aH[m][kk] = *(const bf16x8*)(Ab + (m + 4) * 2048 + kk * 1024 + soff);
    STG(Brow, 0, jb * 64, LDSB(b, 0));
    BARX();
    LGKM0();
    __builtin_amdgcn_s_setprio(1);
#pragma unroll
    for (int m = 0; m < 4; ++m)
#pragma unroll
      for (int n = 0; n < 2; ++n)
#pragma unroll
        for (int kk = 0; kk < 2; ++kk)
          acc[m + 4][n] = mfma16(aH[m][kk], bL[n][kk], acc[m + 4][n]);
    __builtin_amdgcn_s_setprio(0);
    BARX();
    // ---- P4: stage B1(j+2) + A0(j+2); counted vmcnt(6) drains A1(j+1)
    STG(Brow, 1, jb * 64, LDSB(b, 1));
    STG(Arow, 0, jb * 64, LDSA(b, 0));
    asm volatile("s_waitcnt vmcnt(6)" ::: "memory");
    BARX();
    LGKM0();
    __builtin_amdgcn_s_setprio(1);
#pragma unroll
    for (int m = 0; m < 4; ++m)
#pragma unroll
      for (int n = 0; n < 2; ++n)
#pragma unroll
        for (int kk = 0; kk < 2; ++kk)
          acc[m + 4][n + 2] = mfma16(aH[m][kk], bH[n][kk], acc[m + 4][n + 2]);
    __builtin_amdgcn_s_setprio(0);
    BARX();
  }
#pragma unroll
  for (int m = 0; m < 8; ++m)
#pragma unroll
    for (int n = 0; n < 4; ++n) {
      const int row = m0 + wr * 128 + m * 16 + g * 4;
      const int col = n0 + wc * 64 + n * 16 + rr;
#pragma unroll
      for (int jj = 0; jj < 4; ++jj)
        Cz[(size_t)(row + jj) * N + col] = f2bf(acc[m][n][jj]);
    }
#undef LDSA
#undef LDSB
#undef STG
}

// ---------------------- split-K reduce: out = sum_z bf2f(pc[z]) + bias, f32
__global__ __launch_bounds__(256)
void k_red8(const u16* __restrict__ pc, const float* __restrict__ bias,
            float* __restrict__ out) {
  const size_t base = ((size_t)blockIdx.x * 256 + threadIdx.x) * 8;
  float a[8] = {};
#pragma unroll
  for (int z = 0; z < 8; ++z) {
    u16x8 v = *(const u16x8*)(pc + (size_t)z * (2048u * 3072u) + base);
#pragma unroll
    for (int e = 0; e < 8; ++e) a[e] += bf2f(v[e]);
  }
  const int col = (int)(base % 3072);
  fv4 b0 = *(const fv4*)(bias + col), b1 = *(const fv4*)(bias + col + 4);
  fv4 o0, o1;
#pragma unroll
  for (int e = 0; e < 4; ++e) { o0[e] = a[e] + b0[e]; o1[e] = a[4 + e] + b1[e]; }
  *(fv4*)(out + base) = o0;
  *(fv4*)(out + base + 4) = o1;
}

// ------------------------------------- RMSNorm + interleaved RoPE on q,k rows
__global__ __launch_bounds__(256)
void k_qknr(u16* __restrict__ h, const float* __restrict__ cosT,
            const float* __restrict__ sinT, const float* __restrict__ wq,
            const float* __restrict__ wk) {
  const int row = blockIdx.x * 4 + (threadIdx.x >> 6);
  const int lane = threadIdx.x & 63;
  const int s = row / 48;
  const int r2 = row - s * 48;
  const int qk = r2 / 24;
  const int head = r2 - qk * 24;
  u16* base = h + (size_t)s * N1_ + qk * 3072 + head * 128;
  u32 pv = *(const u32*)(base + 2 * lane);
  float x1 = bf2f((u16)(pv & 0xffff)), x2 = bf2f((u16)(pv >> 16));
  float ss = x1 * x1 + x2 * x2;
#pragma unroll
  for (int off = 32; off >= 1; off >>= 1) ss += __shfl_xor(ss, off);
  const float inv = rsqrtf(ss * (1.0f / 128.0f) + 1e-5f);
  const float* wv = qk ? wk : wq;
  const float w1 = wv[2 * lane], w2 = wv[2 * lane + 1];
  const float c = cosT[s * 64 + lane], sn = sinT[s * 64 + lane];
  float xn1 = x1 * inv * w1, xn2 = x2 * inv * w2;
  float r1 = xn1 * c - xn2 * sn;
  float r2v = xn2 * c + xn1 * sn;
  if (!qk) { r1 *= 0.08838834764831845f; r2v *= 0.08838834764831845f; }
  *(u32*)(base + 2 * lane) = (u32)f2bf(r1) | ((u32)f2bf(r2v) << 16);
}

// --------------------------------------------- V^T per head: vt[h*128+d][s]
__global__ __launch_bounds__(256)
void k_vt(const u16* __restrict__ h, u16* __restrict__ vt) {
  __shared__ u16 tile[64][144];
  const int t = threadIdx.x;
  const int head = blockIdx.y;
  const int s0 = blockIdx.x * 64;
  {
    const int sl = t >> 2, cc = t & 3;
    const u16* src = h + (size_t)(s0 + sl) * N1_ + 6144 + head * 128 + cc * 32;
#pragma unroll
    for (int q = 0; q < 4; ++q)
      *(u16x8*)&tile[sl][cc * 32 + q * 8] = *(const u16x8*)(src + q * 8);
  }
  __syncthreads();
  {
    const int d = t & 127, half = t >> 7;
    u16* dst = vt + ((size_t)head * 128 + d) * S_ + s0 + half * 32;
#pragma unroll
    for (int q = 0; q < 4; ++q) {
      u16x8 v;
#pragma unroll
      for (int e = 0; e < 8; ++e) v[e] = tile[half * 32 + q * 8 + e][d];
      *(u16x8*)(dst + q * 8) = v;
    }
  }
}

// ------------------------------------------------------------ flash attention
__global__ __launch_bounds__(256)
void k_attn(const u16* __restrict__ h, const u16* __restrict__ vt,
            u16* __restrict__ cc) {
  extern __shared__ char smem[];
  char* KsB = smem;           // 2 x 16KB
  char* VsB = smem + 32768;   // 2 x 16KB
  const int t = threadIdx.x, w = t >> 6, lane = t & 63;
  const int g = lane >> 4, c = lane & 15;
  u16* Pw = (u16*)(smem + 65536 + w * 2304);  // [16][72]
  const int head = blockIdx.y;
  const int q0 = blockIdx.x * 64 + w * 16;
  const int wb = w * 1024;

  const u16* ksrc[4];
  const u16* vsrc[4];
#pragma unroll
  for (int p = 0; p < 4; ++p) {
    const int o = p * 4096 + wb + lane * 16;
    {
      const int kc = o >> 12, r = (o >> 6) & 63, db = o & 63;
      ksrc[p] = h + (size_t)r * N1_ + 3072 + head * 128 + kc * 32 + db / 2;
    }
    {
      const int ks = o >> 13, d = (o >> 6) & 127, db = o & 63;
      vsrc[p] = vt + (size_t)(head * 128 + d) * S_ + ks * 32 + db / 2;
    }
  }
#define STAGEA(ts, buf)                                                     \
  do {                                                                      \
    const size_t _ka = (size_t)(ts) * 64 * N1_;                             \
    const int _kv = (ts) * 64;                                              \
    _Pragma("unroll") for (int p = 0; p < 4; ++p)                           \
        GLD16(ksrc[p] + _ka, KsB + (buf) * 16384 + p * 4096 + wb);          \
    _Pragma("unroll") for (int p = 0; p < 4; ++p)                           \
        GLD16(vsrc[p] + _kv, VsB + (buf) * 16384 + p * 4096 + wb);          \
  } while (0)

  bf16x8 aq[4];
  {
    const u16* qr = h + (size_t)(q0 + c) * N1_ + head * 128;
#pragma unroll
    for (int kc = 0; kc < 4; ++kc)
      aq[kc] = *reinterpret_cast<const bf16x8*>(qr + kc * 32 + g * 8);
  }
  f32x4 o[8] = {};
  float m_[4] = {-1e30f, -1e30f, -1e30f, -1e30f};
  float l_[4] = {0.f, 0.f, 0.f, 0.f};

  STAGEA(0, 0);
  STAGEA(1, 1);
  asm volatile("s_waitcnt vmcnt(8)" ::: "memory");
  __builtin_amdgcn_s_barrier();

  for (int tt = 0; tt < 32; ++tt) {
    const int buf = tt & 1;
    const char* Kb = KsB + buf * 16384;
    const char* Vb = VsB + buf * 16384;
    f32x4 sc[4] = {};
    __builtin_amdgcn_s_setprio(1);
#pragma unroll
    for (int nf = 0; nf < 4; ++nf)
#pragma unroll
      for (int kc = 0; kc < 4; ++kc) {
        bf16x8 bk = *(const bf16x8*)(Kb + kc * 4096 + (nf * 16 + c) * 64 + g * 16);
        sc[nf] = mfma16(aq[kc], bk, sc[nf]);
      }
    __builtin_amdgcn_s_setprio(0);
    float rmax[4];
#pragma unroll
    for (int j = 0; j < 4; ++j)
      rmax[j] = fmaxf(fmaxf(sc[0][j], sc[1][j]), fmaxf(sc[2][j], sc[3][j]));
#pragma unroll
    for (int j = 0; j < 4; ++j)
#pragma unroll
      for (int off = 8; off >= 1; off >>= 1)
        rmax[j] = fmaxf(rmax[j], __shfl_xor(rmax[j], off));
    float al[4], rs[4];
#pragma unroll
    for (int j = 0; j < 4; ++j) {
      const float mn = fmaxf(m_[j], rmax[j]);
      al[j] = __expf(m_[j] - mn);
      m_[j] = mn;
      rs[j] = 0.f;
    }
#pragma unroll
    for (int nf = 0; nf < 4; ++nf)
#pragma unroll
      for (int j = 0; j < 4; ++j) {
        const float pr = __expf(sc[nf][j] - m_[j]);
        sc[nf][j] = pr;
        rs[j] += pr;
      }
#pragma unroll
    for (int j = 0; j < 4; ++j) {
#pragma unroll
      for (int off = 8; off >= 1; off >>= 1) rs[j] += __shfl_xor(rs[j], off);
      l_[j] = l_[j] * al[j] + rs[j];
    }
#pragma unroll
    for (int of = 0; of < 8; ++of)
#pragma unroll
      for (int j = 0; j < 4; ++j) o[of][j] *= al[j];
#pragma unroll
    for (int nf = 0; nf < 4; ++nf)
#pragma unroll
      for (int j = 0; j < 4; ++j)
        Pw[(g * 4 + j) * 72 + nf * 16 + c] = f2bf(sc[nf][j]);
    asm volatile("s_waitcnt lgkmcnt(0)" ::: "memory");
    bf16x8 ap[2];
#pragma unroll
    for (int ks = 0; ks < 2; ++ks)
      ap[ks] = *(const bf16x8*)(Pw + c * 72 + ks * 32 + g * 8);
    __builtin_amdgcn_s_setprio(1);
#pragma unroll
    for (int of = 0; of < 8; ++of)
#pragma unroll
      for (int ks = 0; ks < 2; ++ks) {
        bf16x8 bv = *(const bf16x8*)(Vb + ks * 8192 + (of * 16 + c) * 64 + g * 16);
        o[of] = mfma16(ap[ks], bv, o[of]);
      }
    __builtin_amdgcn_s_setprio(0);
    __builtin_amdgcn_s_barrier();
    const int tn = (tt + 2 < 32) ? tt + 2 : 31;
    STAGEA(tn, buf);
    asm volatile("s_waitcnt vmcnt(8)" ::: "memory");
    __builtin_amdgcn_s_barrier();
  }
  float inv[4];
#pragma unroll
  for (int j = 0; j < 4; ++j) inv[j] = 1.0f / l_[j];
#pragma unroll
  for (int of = 0; of < 8; ++of)
#pragma unroll
    for (int j = 0; j < 4; ++j)
      cc[(size_t)(q0 + g * 4 + j) * K2_ + head * 128 + of * 16 + c] =
          f2bf(o[of][j] * inv[j]);
#undef STAGEA
}

// --------------------------------------------------- silu(x1)*x2 -> concat
__global__ void k_mlpact(const u16* __restrict__ h, u16* __restrict__ cc) {
  const int i = blockIdx.x * blockDim.x + threadIdx.x;
  const int s = i / 1536;
  const int j8 = i - s * 1536;
  const u16x8 a8 = *((const u16x8*)(h + (size_t)s * N1_ + 9216) + j8);
  const u16x8 b8 = *((const u16x8*)(h + (size_t)s * N1_ + 21504) + j8);
  u16x8 r;
#pragma unroll
  for (int e = 0; e < 8; ++e) {
    float a = bf2f(a8[e]), b = bf2f(b8[e]);
    float sv = a / (1.0f + expf(-a));
    r[e] = f2bf(sv * b);
  }
  *((u16x8*)(cc + (size_t)s * K2_ + 3072) + j8) = r;
}

// ---------------------------------------------------------------------------
extern "C" void kernel_launch(void* const* d_in, const int* in_sizes, int n_in,
                              void* d_out, int out_size, void* d_ws,
                              size_t ws_size, hipStream_t stream) {
  const float* hs   = (const float*)d_in[0];
  const float* cosT = (const float*)d_in[1];
  const float* sinT = (const float*)d_in[2];
  const float* W1   = (const float*)d_in[3];
  const float* wq   = (const float*)d_in[4];
  const float* wk   = (const float*)d_in[5];
  const float* W2   = (const float*)d_in[6];
  const float* bo   = (const float*)d_in[7];
  float* out = (float*)d_out;

  char* p = (char*)d_ws;
  u16* Abf  = (u16*)p; p += (size_t)S_ * K1_ * 2;
  u16* W1t  = (u16*)p; p += (size_t)N1_ * K1_ * 2;   // dead after GEMM1 ->
  u16* W2t  = (u16*)p; p += (size_t)N2_ * K2_ * 2;   // reused for splitK parts
  u16* Hbuf = (u16*)p; p += (size_t)S_ * N1_ * 2;
  u16* Vt   = (u16*)p; p += (size_t)H_ * 128 * S_ * 2;
  u16* CC   = (u16*)p; p += (size_t)S_ * K2_ * 2;
  if ((size_t)(p - (char*)d_ws) > ws_size) return;
  u16* PC = W1t;  // 8 x 2048x3072 bf16 partials = 100.7 MB <= 207.6 MB

  k_cvt<<<(S_ * K1_) / (256 * 8), 256, 0, stream>>>(hs, Abf);
  k_tconv8<<<dim3(N1_ / 128, K1_ / 128), 256, 0, stream>>>(W1, W1t, K1_, N1_);
  k_tconv8<<<dim3(N2_ / 128, K2_ / 128), 256, 0, stream>>>(W2, W2t, K2_, N2_);

  hipError_t aerr = hipFuncSetAttribute(
      reinterpret_cast<const void*>(k_gemm256),
      hipFuncAttributeMaxDynamicSharedMemorySize, 131072);
  if (aerr == hipSuccess) {
    // GEMM1: 8m x 132n, single K-slice (zmul = grid -> zz = 0)
    k_gemm256<<<dim3(1056), 512, 131072, stream>>>(Abf, W1t, Hbuf,
                                                   N1_, K1_, 8, 1056, 48);
  } else {
    k_gemm<128, 128, 64, 64, false>
        <<<dim3(S_ / 128, N1_ / 128), 256, 0, stream>>>(Abf, W1t, Hbuf, nullptr,
                                                        S_, N1_, K1_);
  }
  k_qknr<<<(S_ * 2 * H_) / 4, 256, 0, stream>>>(Hbuf, cosT, sinT, wq, wk);
  k_vt<<<dim3(S_ / 64, H_), 256, 0, stream>>>(Hbuf, Vt);
  (void)hipFuncSetAttribute(reinterpret_cast<const void*>(k_attn),
                            hipFuncAttributeMaxDynamicSharedMemorySize, 75776);
  k_attn<<<dim3(S_ / 64, H_), 256, 75776, stream>>>(Hbuf, Vt, CC);
  k_mlpact<<<(S_ * MLP_) / (256 * 8), 256, 0, stream>>>(Hbuf, CC);
  if (aerr == hipSuccess) {
    // GEMM2: split-K=8 -> grid 8m x 12n x 8z = 768 = exactly 3 block-rounds
    k_gemm256<<<dim3(768), 512, 131072, stream>>>(CC, W2t, PC,
                                                  N2_, K2_, 8, 96, 30);
    k_red8<<<dim3((S_ * N2_) / (256 * 8)), 256, 0, stream>>>(PC, bo, out);
  } else {
    k_gemm<128, 128, 64, 64, true>
        <<<dim3(S_ / 128, N2_ / 128), 256, 0, stream>>>(CC, W2t, out, bo,
                                                        S_, N2_, K2_);
  }
}